// Round 11
// baseline (2253.660 us; speedup 1.0000x reference)
//
#include <hip/hip_runtime.h>
#include <cstdint>
#include <cstddef>

typedef __attribute__((ext_vector_type(8))) _Float16 half8;
typedef __attribute__((ext_vector_type(4))) float f32x4;

#define N_ROWS 16384
#define K_CODES 8192
#define D_DIM 256
#define MARGIN 2.5e-4f
#define SCL (-0.000244140625f) /* -2/8192, exact */
#define CAP 524288u

// ws layout (bytes), total ~6.5 MB
#define WS_EF    0u        /* 8192*256 f16, 128 tiles of [64 codes][256 d] swizzled (4 MB) */
#define WS_WMIN  4194304u  /* 16384 u64 packed (score_bits<<32 | col) */
#define WS_Z2    4325376u  /* 16384 f32 */
#define WS_E2    4390912u  /* 8192  f32 */
#define WS_AMIN  4423680u  /* 16384 u32 float-bits approx min (biased +1 score space) */
#define WS_PART  4489216u  /* 256 f64 loss partials */
#define WS_CNT   4491264u  /* 1 u32 candidate count (+pad) */
#define WS_LIST  4491328u  /* CAP u32 candidates: (row<<13)|col (2 MB) */

__device__ __forceinline__ void gload16(const void* g, void* l) {
    __builtin_amdgcn_global_load_lds(
        (const __attribute__((address_space(1))) void*)g,
        (__attribute__((address_space(3))) void*)l, 16, 0, 0);
}

// ---------------------------------------------------------------------------
// k_prep: row norms z2/e2, init wmin/amin/partials/count
// ---------------------------------------------------------------------------
__global__ __launch_bounds__(256) void k_prep(const float* __restrict__ z,
                                              const float* __restrict__ e,
                                              float* __restrict__ z2,
                                              float* __restrict__ e2,
                                              unsigned long long* __restrict__ wmin,
                                              double* __restrict__ partials,
                                              unsigned* __restrict__ amin,
                                              unsigned* __restrict__ gcount) {
    int tid = threadIdx.x;
    int w = tid >> 6, lane = tid & 63;
    int row = blockIdx.x * 4 + w;
    if (blockIdx.x == 0) {
        partials[tid] = 0.0;
        if (tid == 0) *gcount = 0u;
    }
    const float* src = (row < N_ROWS) ? (z + (size_t)row * D_DIM)
                                      : (e + (size_t)(row - N_ROWS) * D_DIM);
    float4 v = reinterpret_cast<const float4*>(src)[lane];
    float s = v.x * v.x;
    s = fmaf(v.y, v.y, s);
    s = fmaf(v.z, v.z, s);
    s = fmaf(v.w, v.w, s);
    #pragma unroll
    for (int off = 32; off >= 1; off >>= 1) s += __shfl_down(s, off);
    if (lane == 0) {
        if (row < N_ROWS) {
            z2[row] = s;
            wmin[row] = ~0ull;
            amin[row] = 0x7F800000u; // +inf bits
        } else {
            e2[row - N_ROWS] = s;
        }
    }
}

// ---------------------------------------------------------------------------
// k_conv: e fp32 -> f16 (x8192), 128 tiles of [64 codes][256 d], granule-XOR
// swizzled so linear global_load_lds + swizzled ds_read_b128 is conflict-free
// ---------------------------------------------------------------------------
__global__ __launch_bounds__(256) void k_conv(const float* __restrict__ e,
                                              _Float16* __restrict__ ef) {
    int t = blockIdx.x; // 0..127
    const float* src = e + (size_t)t * 64 * D_DIM;
    _Float16* dst = ef + (size_t)t * 16384;
    #pragma unroll
    for (int i = 0; i < 8; ++i) {
        int gid = threadIdx.x + i * 256; // granule 0..2047 (8 f16 each)
        int r = gid >> 5, g = gid & 31;  // code-row 0..63, granule-in-row 0..31
        const float* s = src + (size_t)r * D_DIM + g * 8;
        float4 v0 = ((const float4*)s)[0];
        float4 v1 = ((const float4*)s)[1];
        half8 h;
        h[0] = (_Float16)(v0.x * 8192.0f); h[1] = (_Float16)(v0.y * 8192.0f);
        h[2] = (_Float16)(v0.z * 8192.0f); h[3] = (_Float16)(v0.w * 8192.0f);
        h[4] = (_Float16)(v1.x * 8192.0f); h[5] = (_Float16)(v1.y * 8192.0f);
        h[6] = (_Float16)(v1.z * 8192.0f); h[7] = (_Float16)(v1.w * 8192.0f);
        int dg = r * 32 + (g ^ (r & 7));
        *(half8*)(dst + (size_t)dg * 8) = h;
    }
}

// ---------------------------------------------------------------------------
// k_score: block = 128 rows x 1024 codes. 4 waves, each wave owns 32 rows,
// all 64 codes of the current e-tile. z fragments live in registers for the
// whole block (av[2][8] = 64 VGPR). e-tile staged to 32KB LDS.
// __launch_bounds__(256,2): 256-VGPR cap so av+acc+bv (~150) does NOT spill
// (round-8 post-mortem: default budget 88 VGPR spilled av to scratch ->
//  MfmaUtil 1.3%, 2 ms; the whole kernel was scratch-latency-bound).
// MODE 0: running min -> amin[row] (biased-score bits)
// MODE 1: s <= amin[row]+MARGIN -> append (row,col) to candidate list
// ---------------------------------------------------------------------------
template <int MODE>
__global__ __launch_bounds__(256, 2) void k_score(const float* __restrict__ z,
                                                  const _Float16* __restrict__ ef,
                                                  const float* __restrict__ e2,
                                                  unsigned* __restrict__ amin,
                                                  unsigned* __restrict__ gcount,
                                                  unsigned* __restrict__ list) {
    __shared__ _Float16 Bs[16384]; // 32 KB: [64 codes][256 d] swizzled
    const int tid = threadIdx.x;
    const int wid = tid >> 6, lane = tid & 63;
    const int l15 = lane & 15, l4 = lane >> 4;
    const int row0 = blockIdx.x * 128 + wid * 32;
    const int kbase = blockIdx.y * 1024;

    // A fragments: av[mi][s] = z[row0+mi*16+l15][s*32 + l4*8 .. +8] as f16
    half8 av[2][8];
    #pragma unroll
    for (int mi = 0; mi < 2; ++mi) {
        const float* zr = z + (size_t)(row0 + mi * 16 + l15) * D_DIM + l4 * 8;
        #pragma unroll
        for (int s = 0; s < 8; ++s) {
            float4 a = *(const float4*)(zr + s * 32);
            float4 b = *(const float4*)(zr + s * 32 + 4);
            half8 h;
            h[0] = (_Float16)a.x; h[1] = (_Float16)a.y;
            h[2] = (_Float16)a.z; h[3] = (_Float16)a.w;
            h[4] = (_Float16)b.x; h[5] = (_Float16)b.y;
            h[6] = (_Float16)b.z; h[7] = (_Float16)b.w;
            av[mi][s] = h;
        }
    }

    float rmin[2][4];
    float thr[2][4];
    #pragma unroll
    for (int mi = 0; mi < 2; ++mi)
        #pragma unroll
        for (int r = 0; r < 4; ++r) {
            if (MODE == 0) rmin[mi][r] = __builtin_inff();
            else thr[mi][r] =
                __uint_as_float(amin[row0 + mi * 16 + l4 * 4 + r]) + MARGIN;
        }

    for (int t = 0; t < 16; ++t) {
        const _Float16* et = ef + (size_t)(kbase / 64 + t) * 16384;
        #pragma unroll
        for (int i = 0; i < 8; ++i) {
            int off = i * 4096 + tid * 16; // bytes, linear (swizzle pre-applied)
            gload16((const char*)et + off, (char*)&Bs[0] + off);
        }
        asm volatile("s_waitcnt vmcnt(0)" ::: "memory");
        __syncthreads();

        f32x4 acc[2][4];
        #pragma unroll
        for (int mi = 0; mi < 2; ++mi)
            #pragma unroll
            for (int ni = 0; ni < 4; ++ni) acc[mi][ni] = (f32x4){0.f, 0.f, 0.f, 0.f};

        #pragma unroll
        for (int s = 0; s < 8; ++s) {
            half8 bv[4];
            #pragma unroll
            for (int ni = 0; ni < 4; ++ni) {
                int c = ni * 16 + l15;
                int byte = c * 512 + (((s * 4 + l4) ^ (c & 7)) << 4);
                bv[ni] = *(const half8*)((const char*)&Bs[0] + byte);
            }
            #pragma unroll
            for (int mi = 0; mi < 2; ++mi)
                #pragma unroll
                for (int ni = 0; ni < 4; ++ni)
                    acc[mi][ni] = __builtin_amdgcn_mfma_f32_16x16x32_f16(
                        av[mi][s], bv[ni], acc[mi][ni], 0, 0, 0);
        }

        // epilogue — C/D frag: col = lane&15, row = (lane>>4)*4 + reg
        #pragma unroll
        for (int ni = 0; ni < 4; ++ni) {
            int c = kbase + t * 64 + ni * 16 + l15;
            float e2b = e2[c] + 1.0f; // +1 bias keeps scores positive for u32 min
            #pragma unroll
            for (int mi = 0; mi < 2; ++mi)
                #pragma unroll
                for (int r = 0; r < 4; ++r) {
                    float sc = fmaf(SCL, acc[mi][ni][r], e2b);
                    if (MODE == 0) {
                        rmin[mi][r] = fminf(rmin[mi][r], sc);
                    } else if (sc <= thr[mi][r]) {
                        unsigned pos = atomicAdd(gcount, 1u);
                        if (pos < CAP)
                            list[pos] =
                                ((unsigned)(row0 + mi * 16 + l4 * 4 + r) << 13) |
                                (unsigned)c;
                    }
                }
        }
        __syncthreads();
    }

    if (MODE == 0) {
        #pragma unroll
        for (int mi = 0; mi < 2; ++mi)
            #pragma unroll
            for (int r = 0; r < 4; ++r) {
                float m = rmin[mi][r];
                #pragma unroll
                for (int x = 1; x < 16; x <<= 1) m = fminf(m, __shfl_xor(m, x));
                if (l15 == 0)
                    atomicMin(&amin[row0 + mi * 16 + l4 * 4 + r], __float_as_uint(m));
            }
    }
}

// ---------------------------------------------------------------------------
// k_rescore: one THREAD per candidate; exact sequential-fp32 scoring
// (identical formula to the round-2/3-verified path), packed u64 atomicMin
// ---------------------------------------------------------------------------
__global__ __launch_bounds__(256) void k_rescore(const float* __restrict__ z,
                                                 const float* __restrict__ e,
                                                 const float* __restrict__ z2,
                                                 const float* __restrict__ e2,
                                                 const unsigned* __restrict__ gcount,
                                                 const unsigned* __restrict__ list,
                                                 unsigned long long* __restrict__ wmin) {
    unsigned n = *gcount;
    if (n > CAP) n = CAP;
    for (unsigned i = blockIdx.x * 256 + threadIdx.x; i < n; i += gridDim.x * 256) {
        unsigned v = list[i];
        unsigned row = (v >> 13) & 16383u, col = v & 8191u;
        const float* zp = z + (size_t)row * D_DIM;
        const float* ep = e + (size_t)col * D_DIM;
        float ax = 0.f; // exact: sequential fp32 fma, d ascending
        for (int d = 0; d < D_DIM; ++d) ax = fmaf(zp[d], ep[d], ax);
        float se = fmaf(-2.0f, ax, z2[row] + e2[col]);
        unsigned long long key =
            ((unsigned long long)__float_as_uint(se) << 32) | col;
        atomicMin(&wmin[row], key);
    }
}

// ---------------------------------------------------------------------------
__global__ __launch_bounds__(64) void k_gather(const float* __restrict__ z,
                                               const float* __restrict__ e,
                                               const unsigned long long* __restrict__ wmin,
                                               float* __restrict__ out,
                                               double* __restrict__ partials) {
    int row = blockIdx.x;
    int lane = threadIdx.x;
    // clamp: if wmin were ever unset (broken invariant), read in-bounds garbage
    // and fail correctness cleanly instead of faulting the GPU
    unsigned idx = (unsigned)(wmin[row] & 0xFFFFFFFFull) & 8191u;
    float4 q = reinterpret_cast<const float4*>(e + (size_t)idx * D_DIM)[lane];
    float4 zv = reinterpret_cast<const float4*>(z + (size_t)row * D_DIM)[lane];
    float dx = q.x - zv.x, dy = q.y - zv.y, dz = q.z - zv.z, dw = q.w - zv.w;
    float4 o;
    o.x = zv.x + dx; o.y = zv.y + dy; o.z = zv.z + dz; o.w = zv.w + dw;
    reinterpret_cast<float4*>(out + (size_t)row * D_DIM)[lane] = o;
    float s = dx * dx;
    s = fmaf(dy, dy, s);
    s = fmaf(dz, dz, s);
    s = fmaf(dw, dw, s);
    #pragma unroll
    for (int off = 32; off >= 1; off >>= 1) s += __shfl_down(s, off);
    if (lane == 0) atomicAdd(&partials[row & 255], (double)s);
}

__global__ __launch_bounds__(64) void k_finalize(const double* __restrict__ partials,
                                                 float* __restrict__ out_loss) {
    int lane = threadIdx.x;
    double v = partials[lane] + partials[lane + 64] +
               partials[lane + 128] + partials[lane + 192];
    #pragma unroll
    for (int off = 32; off >= 1; off >>= 1) v += __shfl_down(v, off);
    if (lane == 0) {
        float L = (float)(v / (double)((size_t)N_ROWS * D_DIM));
        out_loss[0] = L + 0.25f * L;
    }
}

extern "C" void kernel_launch(void* const* d_in, const int* in_sizes, int n_in,
                              void* d_out, int out_size, void* d_ws, size_t ws_size,
                              hipStream_t stream) {
    const float* z = (const float*)d_in[0]; // [16384, 256]
    const float* e = (const float*)d_in[1]; // [8192, 256]
    float* out = (float*)d_out;             // 4194304 z_q_st + 1 loss
    char* ws = (char*)d_ws;

    _Float16* ef = (_Float16*)(ws + WS_EF);
    unsigned long long* wmin = (unsigned long long*)(ws + WS_WMIN);
    float* z2 = (float*)(ws + WS_Z2);
    float* e2 = (float*)(ws + WS_E2);
    unsigned* amin = (unsigned*)(ws + WS_AMIN);
    double* partials = (double*)(ws + WS_PART);
    unsigned* gcount = (unsigned*)(ws + WS_CNT);
    unsigned* list = (unsigned*)(ws + WS_LIST);

    k_prep<<<(N_ROWS + K_CODES) / 4, 256, 0, stream>>>(z, e, z2, e2, wmin,
                                                       partials, amin, gcount);
    k_conv<<<128, 256, 0, stream>>>(e, ef);
    k_score<0><<<dim3(128, 1), 256, 0, stream>>>(z, ef, e2, amin, gcount, list);
    k_score<1><<<dim3(128, 8), 256, 0, stream>>>(z, ef, e2, amin, gcount, list);
    k_rescore<<<256, 256, 0, stream>>>(z, e, z2, e2, gcount, list, wmin);
    k_gather<<<N_ROWS, 64, 0, stream>>>(z, e, wmin, out, partials);
    k_finalize<<<1, 64, 0, stream>>>(partials, out + (size_t)N_ROWS * D_DIM);
}

// Round 12
// 289.668 us; speedup vs baseline: 7.7802x; 7.7802x over previous
//
#include <hip/hip_runtime.h>
#include <cstdint>
#include <cstddef>

typedef __attribute__((ext_vector_type(8))) _Float16 half8;
typedef __attribute__((ext_vector_type(4))) float f32x4;

#define N_ROWS 16384
#define K_CODES 8192
#define D_DIM 256
#define MARGIN 2.5e-4f
#define SCL (-0.000244140625f) /* -2/8192, exact */
#define NSEG 1024u
#define SEG 512u

// ws layout (bytes), total ~6.6 MB
#define WS_EF    0u        /* 8192*256 f16, 128 tiles of [64 codes][256 d] swizzled (4 MB) */
#define WS_WMIN  4194304u  /* 16384 u64 packed (score_bits<<32 | col) */
#define WS_Z2    4325376u  /* 16384 f32 */
#define WS_E2    4390912u  /* 8192  f32 */
#define WS_AMIN  4423680u  /* 16384 u32 float-bits approx min (biased +1 score space) */
#define WS_PART  4489216u  /* 256 f64 loss partials */
#define WS_CNT   4491264u  /* 1024 u32 per-segment candidate counts (4 KB) */
#define WS_LIST  4495360u  /* 1024 segments x 512 u32 candidates: (row<<13)|col (2 MB) */

__device__ __forceinline__ void gload16(const void* g, void* l) {
    __builtin_amdgcn_global_load_lds(
        (const __attribute__((address_space(1))) void*)g,
        (__attribute__((address_space(3))) void*)l, 16, 0, 0);
}

// ---------------------------------------------------------------------------
// k_prep: row norms z2/e2, init wmin/amin/partials/segment counts
// ---------------------------------------------------------------------------
__global__ __launch_bounds__(256) void k_prep(const float* __restrict__ z,
                                              const float* __restrict__ e,
                                              float* __restrict__ z2,
                                              float* __restrict__ e2,
                                              unsigned long long* __restrict__ wmin,
                                              double* __restrict__ partials,
                                              unsigned* __restrict__ amin,
                                              unsigned* __restrict__ cnt) {
    int tid = threadIdx.x;
    int w = tid >> 6, lane = tid & 63;
    int row = blockIdx.x * 4 + w;
    if (blockIdx.x == 0) partials[tid] = 0.0;
    if (blockIdx.x < 4) cnt[blockIdx.x * 256 + tid] = 0u;
    const float* src = (row < N_ROWS) ? (z + (size_t)row * D_DIM)
                                      : (e + (size_t)(row - N_ROWS) * D_DIM);
    float4 v = reinterpret_cast<const float4*>(src)[lane];
    float s = v.x * v.x;
    s = fmaf(v.y, v.y, s);
    s = fmaf(v.z, v.z, s);
    s = fmaf(v.w, v.w, s);
    #pragma unroll
    for (int off = 32; off >= 1; off >>= 1) s += __shfl_down(s, off);
    if (lane == 0) {
        if (row < N_ROWS) {
            z2[row] = s;
            wmin[row] = ~0ull;
            amin[row] = 0x7F800000u; // +inf bits
        } else {
            e2[row - N_ROWS] = s;
        }
    }
}

// ---------------------------------------------------------------------------
// k_conv: e fp32 -> f16 (x8192), 128 tiles of [64 codes][256 d], granule-XOR
// swizzled so linear global_load_lds + swizzled ds_read_b128 is conflict-free
// ---------------------------------------------------------------------------
__global__ __launch_bounds__(256) void k_conv(const float* __restrict__ e,
                                              _Float16* __restrict__ ef) {
    int t = blockIdx.x; // 0..127
    const float* src = e + (size_t)t * 64 * D_DIM;
    _Float16* dst = ef + (size_t)t * 16384;
    #pragma unroll
    for (int i = 0; i < 8; ++i) {
        int gid = threadIdx.x + i * 256; // granule 0..2047 (8 f16 each)
        int r = gid >> 5, g = gid & 31;  // code-row 0..63, granule-in-row 0..31
        const float* s = src + (size_t)r * D_DIM + g * 8;
        float4 v0 = ((const float4*)s)[0];
        float4 v1 = ((const float4*)s)[1];
        half8 h;
        h[0] = (_Float16)(v0.x * 8192.0f); h[1] = (_Float16)(v0.y * 8192.0f);
        h[2] = (_Float16)(v0.z * 8192.0f); h[3] = (_Float16)(v0.w * 8192.0f);
        h[4] = (_Float16)(v1.x * 8192.0f); h[5] = (_Float16)(v1.y * 8192.0f);
        h[6] = (_Float16)(v1.z * 8192.0f); h[7] = (_Float16)(v1.w * 8192.0f);
        int dg = r * 32 + (g ^ (r & 7));
        *(half8*)(dst + (size_t)dg * 8) = h;
    }
}

// ---------------------------------------------------------------------------
// k_score: block = 128 rows x 1024 codes. 4 waves; av z-fragments in regs.
// ROUND-12 CHANGE: candidate append now goes through a per-block LDS counter
// into a per-block PRIVATE list segment. Round 8/11 post-mortem: the single
// grid-global atomicAdd(gcount) (~40K value-returning same-address atomics,
// barrier-synchronized bursts) serialized the whole GPU at the coherence
// point -> all pipes <1.5% busy, 2 ms, duration invariant to regalloc.
// MODE 0: running min -> amin[row] (biased-score bits)
// MODE 1: s <= amin[row]+MARGIN -> append (row,col) to private segment
// ---------------------------------------------------------------------------
template <int MODE>
__global__ __launch_bounds__(256, 2) void k_score(const float* __restrict__ z,
                                                  const _Float16* __restrict__ ef,
                                                  const float* __restrict__ e2,
                                                  unsigned* __restrict__ amin,
                                                  unsigned* __restrict__ cnt,
                                                  unsigned* __restrict__ list) {
    __shared__ _Float16 Bs[16384]; // 32 KB: [64 codes][256 d] swizzled
    __shared__ unsigned bcnt;
    const int tid = threadIdx.x;
    const int wid = tid >> 6, lane = tid & 63;
    const int l15 = lane & 15, l4 = lane >> 4;
    const int row0 = blockIdx.x * 128 + wid * 32;
    const int kbase = blockIdx.y * 1024;
    const unsigned segid = blockIdx.y * 128 + blockIdx.x; // MODE 1 only
    unsigned* seg = list + (size_t)segid * SEG;
    if (MODE == 1 && tid == 0) bcnt = 0u;

    // A fragments: av[mi][s] = z[row0+mi*16+l15][s*32 + l4*8 .. +8] as f16
    half8 av[2][8];
    #pragma unroll
    for (int mi = 0; mi < 2; ++mi) {
        const float* zr = z + (size_t)(row0 + mi * 16 + l15) * D_DIM + l4 * 8;
        #pragma unroll
        for (int s = 0; s < 8; ++s) {
            float4 a = *(const float4*)(zr + s * 32);
            float4 b = *(const float4*)(zr + s * 32 + 4);
            half8 h;
            h[0] = (_Float16)a.x; h[1] = (_Float16)a.y;
            h[2] = (_Float16)a.z; h[3] = (_Float16)a.w;
            h[4] = (_Float16)b.x; h[5] = (_Float16)b.y;
            h[6] = (_Float16)b.z; h[7] = (_Float16)b.w;
            av[mi][s] = h;
        }
    }

    float rmin[2][4];
    float thr[2][4];
    #pragma unroll
    for (int mi = 0; mi < 2; ++mi)
        #pragma unroll
        for (int r = 0; r < 4; ++r) {
            if (MODE == 0) rmin[mi][r] = __builtin_inff();
            else thr[mi][r] =
                __uint_as_float(amin[row0 + mi * 16 + l4 * 4 + r]) + MARGIN;
        }

    for (int t = 0; t < 16; ++t) {
        const _Float16* et = ef + (size_t)(kbase / 64 + t) * 16384;
        #pragma unroll
        for (int i = 0; i < 8; ++i) {
            int off = i * 4096 + tid * 16; // bytes, linear (swizzle pre-applied)
            gload16((const char*)et + off, (char*)&Bs[0] + off);
        }
        asm volatile("s_waitcnt vmcnt(0)" ::: "memory");
        __syncthreads();

        f32x4 acc[2][4];
        #pragma unroll
        for (int mi = 0; mi < 2; ++mi)
            #pragma unroll
            for (int ni = 0; ni < 4; ++ni) acc[mi][ni] = (f32x4){0.f, 0.f, 0.f, 0.f};

        #pragma unroll
        for (int s = 0; s < 8; ++s) {
            half8 bv[4];
            #pragma unroll
            for (int ni = 0; ni < 4; ++ni) {
                int c = ni * 16 + l15;
                int byte = c * 512 + (((s * 4 + l4) ^ (c & 7)) << 4);
                bv[ni] = *(const half8*)((const char*)&Bs[0] + byte);
            }
            #pragma unroll
            for (int mi = 0; mi < 2; ++mi)
                #pragma unroll
                for (int ni = 0; ni < 4; ++ni)
                    acc[mi][ni] = __builtin_amdgcn_mfma_f32_16x16x32_f16(
                        av[mi][s], bv[ni], acc[mi][ni], 0, 0, 0);
        }

        // epilogue — C/D frag: col = lane&15, row = (lane>>4)*4 + reg
        #pragma unroll
        for (int ni = 0; ni < 4; ++ni) {
            int c = kbase + t * 64 + ni * 16 + l15;
            float e2b = e2[c] + 1.0f; // +1 bias keeps scores positive for u32 min
            #pragma unroll
            for (int mi = 0; mi < 2; ++mi)
                #pragma unroll
                for (int r = 0; r < 4; ++r) {
                    float sc = fmaf(SCL, acc[mi][ni][r], e2b);
                    if (MODE == 0) {
                        rmin[mi][r] = fminf(rmin[mi][r], sc);
                    } else if (sc <= thr[mi][r]) {
                        unsigned pos = atomicAdd(&bcnt, 1u); // LDS, block-local
                        if (pos < SEG)
                            seg[pos] =
                                ((unsigned)(row0 + mi * 16 + l4 * 4 + r) << 13) |
                                (unsigned)c;
                    }
                }
        }
        __syncthreads();
    }

    if (MODE == 0) {
        #pragma unroll
        for (int mi = 0; mi < 2; ++mi)
            #pragma unroll
            for (int r = 0; r < 4; ++r) {
                float m = rmin[mi][r];
                #pragma unroll
                for (int x = 1; x < 16; x <<= 1) m = fminf(m, __shfl_xor(m, x));
                if (l15 == 0)
                    atomicMin(&amin[row0 + mi * 16 + l4 * 4 + r], __float_as_uint(m));
            }
    } else {
        if (tid == 0) cnt[segid] = (bcnt < SEG) ? bcnt : SEG;
    }
}

// ---------------------------------------------------------------------------
// k_rescore: block b walks private segment b; one THREAD per candidate;
// exact sequential-fp32 scoring (round-2-verified), packed u64 atomicMin
// ---------------------------------------------------------------------------
__global__ __launch_bounds__(256) void k_rescore(const float* __restrict__ z,
                                                 const float* __restrict__ e,
                                                 const float* __restrict__ z2,
                                                 const float* __restrict__ e2,
                                                 const unsigned* __restrict__ cnt,
                                                 const unsigned* __restrict__ list,
                                                 unsigned long long* __restrict__ wmin) {
    unsigned b = blockIdx.x;
    unsigned n = cnt[b];
    if (n > SEG) n = SEG;
    const unsigned* seg = list + (size_t)b * SEG;
    for (unsigned i = threadIdx.x; i < n; i += 256) {
        unsigned v = seg[i];
        unsigned row = (v >> 13) & 16383u, col = v & 8191u;
        const float* zp = z + (size_t)row * D_DIM;
        const float* ep = e + (size_t)col * D_DIM;
        float ax = 0.f; // exact: sequential fp32 fma, d ascending
        for (int d = 0; d < D_DIM; ++d) ax = fmaf(zp[d], ep[d], ax);
        float se = fmaf(-2.0f, ax, z2[row] + e2[col]);
        unsigned long long key =
            ((unsigned long long)__float_as_uint(se) << 32) | col;
        atomicMin(&wmin[row], key);
    }
}

// ---------------------------------------------------------------------------
__global__ __launch_bounds__(64) void k_gather(const float* __restrict__ z,
                                               const float* __restrict__ e,
                                               const unsigned long long* __restrict__ wmin,
                                               float* __restrict__ out,
                                               double* __restrict__ partials) {
    int row = blockIdx.x;
    int lane = threadIdx.x;
    // clamp: if wmin were ever unset (broken invariant), read in-bounds garbage
    // and fail correctness cleanly instead of faulting the GPU
    unsigned idx = (unsigned)(wmin[row] & 0xFFFFFFFFull) & 8191u;
    float4 q = reinterpret_cast<const float4*>(e + (size_t)idx * D_DIM)[lane];
    float4 zv = reinterpret_cast<const float4*>(z + (size_t)row * D_DIM)[lane];
    float dx = q.x - zv.x, dy = q.y - zv.y, dz = q.z - zv.z, dw = q.w - zv.w;
    float4 o;
    o.x = zv.x + dx; o.y = zv.y + dy; o.z = zv.z + dz; o.w = zv.w + dw;
    reinterpret_cast<float4*>(out + (size_t)row * D_DIM)[lane] = o;
    float s = dx * dx;
    s = fmaf(dy, dy, s);
    s = fmaf(dz, dz, s);
    s = fmaf(dw, dw, s);
    #pragma unroll
    for (int off = 32; off >= 1; off >>= 1) s += __shfl_down(s, off);
    if (lane == 0) atomicAdd(&partials[row & 255], (double)s);
}

__global__ __launch_bounds__(64) void k_finalize(const double* __restrict__ partials,
                                                 float* __restrict__ out_loss) {
    int lane = threadIdx.x;
    double v = partials[lane] + partials[lane + 64] +
               partials[lane + 128] + partials[lane + 192];
    #pragma unroll
    for (int off = 32; off >= 1; off >>= 1) v += __shfl_down(v, off);
    if (lane == 0) {
        float L = (float)(v / (double)((size_t)N_ROWS * D_DIM));
        out_loss[0] = L + 0.25f * L;
    }
}

extern "C" void kernel_launch(void* const* d_in, const int* in_sizes, int n_in,
                              void* d_out, int out_size, void* d_ws, size_t ws_size,
                              hipStream_t stream) {
    const float* z = (const float*)d_in[0]; // [16384, 256]
    const float* e = (const float*)d_in[1]; // [8192, 256]
    float* out = (float*)d_out;             // 4194304 z_q_st + 1 loss
    char* ws = (char*)d_ws;

    _Float16* ef = (_Float16*)(ws + WS_EF);
    unsigned long long* wmin = (unsigned long long*)(ws + WS_WMIN);
    float* z2 = (float*)(ws + WS_Z2);
    float* e2 = (float*)(ws + WS_E2);
    unsigned* amin = (unsigned*)(ws + WS_AMIN);
    double* partials = (double*)(ws + WS_PART);
    unsigned* cnt = (unsigned*)(ws + WS_CNT);
    unsigned* list = (unsigned*)(ws + WS_LIST);

    k_prep<<<(N_ROWS + K_CODES) / 4, 256, 0, stream>>>(z, e, z2, e2, wmin,
                                                       partials, amin, cnt);
    k_conv<<<128, 256, 0, stream>>>(e, ef);
    k_score<0><<<dim3(128, 1), 256, 0, stream>>>(z, ef, e2, amin, cnt, list);
    k_score<1><<<dim3(128, 8), 256, 0, stream>>>(z, ef, e2, amin, cnt, list);
    k_rescore<<<NSEG, 256, 0, stream>>>(z, e, z2, e2, cnt, list, wmin);
    k_gather<<<N_ROWS, 64, 0, stream>>>(z, e, wmin, out, partials);
    k_finalize<<<1, 64, 0, stream>>>(partials, out + (size_t)N_ROWS * D_DIM);
}